// Round 8
// baseline (504.478 us; speedup 1.0000x reference)
//
#include <hip/hip_runtime.h>
#include <hip/hip_bf16.h>
#include <stdint.h>

#define NP 409600
#define HG 640
#define WG 640
#define HW (HG*WG)
// padded dense grid per batch: (640+2) x (640+2) pixels, 64 bf16 channels = 128B/pixel
#define WP 642
#define HP 642
#define NPIX (WP*HP)          // 412,164 pixels -> 52,756,992 B per dense buffer

typedef __bf16 bf16x8 __attribute__((ext_vector_type(8)));
typedef float f32x4 __attribute__((ext_vector_type(4)));

// ---------------- prep kernels ----------------

// weights pre-cast to bf16 in PER-LANE FRAGMENT order (r5/r6/r7-verified):
// flat o = (((t*2+ks)*4 + c)*64 + lane)*8 + e  holds
// w[t][k = ks*32 + (lane>>4)*8 + e][n = c*16 + (lane&15)]
__global__ void cast_w_kernel(const float* __restrict__ w1, const float* __restrict__ w2,
                              const float* __restrict__ wd,
                              __hip_bfloat16* __restrict__ wc1, __hip_bfloat16* __restrict__ wc2) {
    int i = blockIdx.x * 256 + threadIdx.x;   // grid = 77824 threads exactly
    if (i < 9*4096) {
        int o = i;
        int e = o & 7, l = (o >> 3) & 63, c = (o >> 9) & 3, ks = (o >> 11) & 1, t = o >> 12;
        int n = c*16 + (l & 15), k = ks*32 + (l >> 4)*8 + e;
        wc1[o] = __float2bfloat16(w1[t*4096 + k*64 + n]);
    }
    int j = i - 9*4096;
    if (j >= 0 && j < 10*4096) {
        int o = j;
        int e = o & 7, l = (o >> 3) & 63, c = (o >> 9) & 3, ks = (o >> 11) & 1, t = o >> 12;
        int n = c*16 + (l & 15), k = ks*32 + (l >> 4)*8 + e;
        float v = (t < 9) ? w2[t*4096 + k*64 + n] : wd[k*64 + n];
        wc2[o] = __float2bfloat16(v);
    }
}

// zero the border ring of the dense y1 buffer ONCE (conv1 writes interior only;
// border must read as zero for conv2's taps). 2564 border pixels x 128B.
__global__ void clear_border_kernel(__hip_bfloat16* __restrict__ y1) {
    int t = blockIdx.x * 256 + threadIdx.x;
    if (t >= 2564*16) return;
    int p = t >> 4, w = t & 15;             // 16 threads/pixel, 8B each
    int yy, xx;
    if (p < 642)        { yy = 0;   xx = p; }
    else if (p < 1284)  { yy = 641; xx = p - 642; }
    else { int q = p - 1284; yy = 1 + (q >> 1); xx = (q & 1) ? 641 : 0; }
    long pp = (long)yy*WP + xx;
    *(uint2*)((char*)y1 + pp*128 + w*8) = make_uint2(0u, 0u);
}

// scatter one batch's points onto the dense padded grid (bf16 cast) + occupancy map.
// 8 threads per point; feature reads coalesced, dense writes are 128B rows.
__global__ void scatter_dense_kernel(const float* __restrict__ f, const int* __restrict__ coords,
                                     int batch, __hip_bfloat16* __restrict__ D,
                                     int* __restrict__ grid) {
    int t = blockIdx.x * 256 + threadIdx.x;   // 12800 blocks = NP*8 threads
    int i = t >> 3, part = t & 7;
    int b = coords[3*i];
    if (b != batch) return;
    int yy = coords[3*i+1], xx = coords[3*i+2];
    if (part == 0) grid[yy*WG + xx] = i;      // original id
    long pp = (long)(yy+1)*WP + (xx+1);
    const float4* p = (const float4*)(f + (long)i*64 + part*8);
    float4 a = p[0], bq = p[1];
    union { uint4 q; __hip_bfloat16 h[8]; } u;
    u.h[0] = __float2bfloat16(a.x);  u.h[1] = __float2bfloat16(a.y);
    u.h[2] = __float2bfloat16(a.z);  u.h[3] = __float2bfloat16(a.w);
    u.h[4] = __float2bfloat16(bq.x); u.h[5] = __float2bfloat16(bq.y);
    u.h[6] = __float2bfloat16(bq.z); u.h[7] = __float2bfloat16(bq.w);
    *(uint4*)(D + pp*64 + part*8) = u.q;
}

// ---------------- DENSE conv kernel (no gather, no indices) ----------------
// One block = 128 consecutive x in one y row (strip). 4 waves, wave w owns
// pixels [w*32, w*32+32) of the strip + a PRIVATE 32x72 LDS slice (r7-proven,
// barrier-free). Every tap's A-tile is a CONTIGUOUS 4KB block at compile-time
// offset (dy*WP+dx)*128B -- no nbr table, no masks (zero border), perfect
// coalescing, compiler can pipeline loads arbitrarily deep.
// Submanifold semantics: D/y1 hold zeros at empty cells; conv1 stores
// occ ? relu(v+b1) : 0 so conv2's taps see zeros at empty neighbors.
// FINAL: residual tap from dense D (contiguous rows, direct fragment loads,
// r6-verified); epilogue scatters to original order via grid (occ only).

#define LDA 72

template<bool FINAL>
__launch_bounds__(256)
__global__ void conv_dense_kernel(const __hip_bfloat16* __restrict__ src,   // padded dense input
                                  const __hip_bfloat16* __restrict__ idsrc, // padded dense D (FINAL)
                                  const int* __restrict__ grid,             // [HW] orig id or -1
                                  const __hip_bfloat16* __restrict__ wT,    // fragment-ordered weights
                                  const float* __restrict__ bias,
                                  __hip_bfloat16* __restrict__ out_bf,      // padded dense y1 (conv1)
                                  float* __restrict__ out_f) {              // original order (conv2)
    __shared__ __align__(16) __hip_bfloat16 As[4][32 * LDA];   // 18,432 B

    const int tid = threadIdx.x;
    // XCD swizzle: 3200 strips, 8 XCDs, 400 contiguous strips (80 y-rows) per XCD
    const int sbid = (blockIdx.x & 7) * 400 + (blockIdx.x >> 3);
    const int y  = sbid / 5;              // output row 0..639
    const int xb = (sbid % 5) * 128;      // strip start x
    const int wave = tid >> 6, lane = tid & 63;
    const int mrow = lane & 15, kq = lane >> 4;
    const int sr = lane >> 3, sc = lane & 7;
    const int lbyte = sr*144 + sc*16;     // LDS byte offset (row sr within chunk, col sc)

    const long pw0 = (long)(y+1)*WP + (xb+1);     // padded pixel of strip row 0
    const long pw  = pw0 + wave*32;               // this wave's first pixel

    __hip_bfloat16* Aw = As[wave];
    char* ab = (char*)Aw;
    const bf16x8* wfrag = (const bf16x8*)wT;

    f32x4 acc[2][4];
    #pragma unroll
    for (int i = 0; i < 2; ++i)
        #pragma unroll
        for (int j = 0; j < 4; ++j)
            acc[i][j] = (f32x4){0.f, 0.f, 0.f, 0.f};

    #pragma unroll
    for (int t = 0; t < 9; ++t) {
        const int doff = (t/3 - 1)*WP + (t%3 - 1);
        const char* rb = (const char*)(src + (pw + doff)*64) + lane*16;
        // 4 contiguous 1KB chunk loads (chunk j = rows j*8..j*8+8 of the 32-row tile)
        uint4 c0 = *(const uint4*)(rb);
        uint4 c1 = *(const uint4*)(rb + 1024);
        uint4 c2 = *(const uint4*)(rb + 2048);
        uint4 c3 = *(const uint4*)(rb + 3072);
        *(uint4*)(ab + 0*1152 + lbyte) = c0;
        *(uint4*)(ab + 1*1152 + lbyte) = c1;
        *(uint4*)(ab + 2*1152 + lbyte) = c2;
        *(uint4*)(ab + 3*1152 + lbyte) = c3;

        __builtin_amdgcn_s_setprio(1);
        #pragma unroll
        for (int ks = 0; ks < 2; ++ks) {
            int kb = ks*32 + kq*8;
            bf16x8 a0 = *(const bf16x8*)(Aw + (     mrow)*LDA + kb);
            bf16x8 a1 = *(const bf16x8*)(Aw + (16 + mrow)*LDA + kb);
            int fb = ((t*2 + ks)*4)*64 + lane;
            bf16x8 b0 = wfrag[fb];
            bf16x8 b1 = wfrag[fb + 64];
            bf16x8 b2 = wfrag[fb + 128];
            bf16x8 b3 = wfrag[fb + 192];
            acc[0][0] = __builtin_amdgcn_mfma_f32_16x16x32_bf16(a0, b0, acc[0][0], 0, 0, 0);
            acc[0][1] = __builtin_amdgcn_mfma_f32_16x16x32_bf16(a0, b1, acc[0][1], 0, 0, 0);
            acc[0][2] = __builtin_amdgcn_mfma_f32_16x16x32_bf16(a0, b2, acc[0][2], 0, 0, 0);
            acc[0][3] = __builtin_amdgcn_mfma_f32_16x16x32_bf16(a0, b3, acc[0][3], 0, 0, 0);
            acc[1][0] = __builtin_amdgcn_mfma_f32_16x16x32_bf16(a1, b0, acc[1][0], 0, 0, 0);
            acc[1][1] = __builtin_amdgcn_mfma_f32_16x16x32_bf16(a1, b1, acc[1][1], 0, 0, 0);
            acc[1][2] = __builtin_amdgcn_mfma_f32_16x16x32_bf16(a1, b2, acc[1][2], 0, 0, 0);
            acc[1][3] = __builtin_amdgcn_mfma_f32_16x16x32_bf16(a1, b3, acc[1][3], 0, 0, 0);
        }
        __builtin_amdgcn_s_setprio(0);
    }

    const int col = mrow, quad = kq;

    // occupancy / output-id lookup for this lane's 8 output rows (contiguous range, L1-hot)
    int oid[2][4];
    #pragma unroll
    for (int mb = 0; mb < 2; ++mb)
        #pragma unroll
        for (int r = 0; r < 4; ++r) {
            int m = wave*32 + mb*16 + quad*4 + r;       // 0..127 within strip
            oid[mb][r] = grid[y*WG + xb + m];
        }

    if (FINAL) {
        // residual tap: contiguous dense D rows @ wd, direct fragment loads (no LDS)
        f32x4 accR[2][4];
        #pragma unroll
        for (int i = 0; i < 2; ++i)
            #pragma unroll
            for (int j = 0; j < 4; ++j)
                accR[i][j] = (f32x4){0.f, 0.f, 0.f, 0.f};
        const long pr0 = pw + mrow, pr1 = pw + 16 + mrow;
        #pragma unroll
        for (int ks = 0; ks < 2; ++ks) {
            int kb = ks*32 + kq*8;
            union { uint4 q; bf16x8 v; } ua0, ua1;
            ua0.q = *(const uint4*)(idsrc + pr0*64 + kb);
            ua1.q = *(const uint4*)(idsrc + pr1*64 + kb);
            int fb = ((9*2 + ks)*4)*64 + lane;
            bf16x8 b0 = wfrag[fb];
            bf16x8 b1 = wfrag[fb + 64];
            bf16x8 b2 = wfrag[fb + 128];
            bf16x8 b3 = wfrag[fb + 192];
            accR[0][0] = __builtin_amdgcn_mfma_f32_16x16x32_bf16(ua0.v, b0, accR[0][0], 0, 0, 0);
            accR[0][1] = __builtin_amdgcn_mfma_f32_16x16x32_bf16(ua0.v, b1, accR[0][1], 0, 0, 0);
            accR[0][2] = __builtin_amdgcn_mfma_f32_16x16x32_bf16(ua0.v, b2, accR[0][2], 0, 0, 0);
            accR[0][3] = __builtin_amdgcn_mfma_f32_16x16x32_bf16(ua0.v, b3, accR[0][3], 0, 0, 0);
            accR[1][0] = __builtin_amdgcn_mfma_f32_16x16x32_bf16(ua1.v, b0, accR[1][0], 0, 0, 0);
            accR[1][1] = __builtin_amdgcn_mfma_f32_16x16x32_bf16(ua1.v, b1, accR[1][1], 0, 0, 0);
            accR[1][2] = __builtin_amdgcn_mfma_f32_16x16x32_bf16(ua1.v, b2, accR[1][2], 0, 0, 0);
            accR[1][3] = __builtin_amdgcn_mfma_f32_16x16x32_bf16(ua1.v, b3, accR[1][3], 0, 0, 0);
        }
        #pragma unroll
        for (int cb = 0; cb < 4; ++cb) {
            float bv = bias[cb*16 + col];
            #pragma unroll
            for (int mb = 0; mb < 2; ++mb) {
                #pragma unroll
                for (int r = 0; r < 4; ++r) {
                    if (oid[mb][r] >= 0) {
                        float v = acc[mb][cb][r] + bv;
                        v = v > 0.f ? v : 0.f;
                        v += accR[mb][cb][r];      // residual added AFTER inner relu
                        v = v > 0.f ? v : 0.f;
                        out_f[(long)oid[mb][r]*64 + cb*16 + col] = v;
                    }
                }
            }
        }
    } else {
        #pragma unroll
        for (int cb = 0; cb < 4; ++cb) {
            float bv = bias[cb*16 + col];
            #pragma unroll
            for (int mb = 0; mb < 2; ++mb) {
                #pragma unroll
                for (int r = 0; r < 4; ++r) {
                    int m = wave*32 + mb*16 + quad*4 + r;
                    float v = acc[mb][cb][r] + bv;
                    v = v > 0.f ? v : 0.f;
                    // store 0 at empty cells: conv2's taps must see zeros there
                    __hip_bfloat16 hv = (oid[mb][r] >= 0) ? __float2bfloat16(v)
                                                          : __float2bfloat16(0.f);
                    out_bf[(pw0 + m)*64 + cb*16 + col] = hv;
                }
            }
        }
    }
}

// ---------------- launch ----------------

extern "C" void kernel_launch(void* const* d_in, const int* in_sizes, int n_in,
                              void* d_out, int out_size, void* d_ws, size_t ws_size,
                              hipStream_t stream) {
    const float* features = (const float*)d_in[0];
    const int*   coords   = (const int*)d_in[1];
    const float* w1 = (const float*)d_in[2];
    const float* b1 = (const float*)d_in[3];
    const float* w2 = (const float*)d_in[4];
    const float* b2 = (const float*)d_in[5];
    const float* wd = (const float*)d_in[6];
    float* out = (float*)d_out;

    char* ws = (char*)d_ws;
    __hip_bfloat16* D    = (__hip_bfloat16*)ws;                   // 52,756,992 B (padded dense)
    __hip_bfloat16* y1d  = (__hip_bfloat16*)(ws + 52756992);      // 52,756,992 B
    int*            grid = (int*)(ws + 105513984);                //  1,638,400 B (orig ids)
    __hip_bfloat16* wc1  = (__hip_bfloat16*)(ws + 107152384);     //     73,728 B
    __hip_bfloat16* wc2  = (__hip_bfloat16*)(ws + 107226112);     //     81,920 B
    // total 107,308,032 B (fits the 123 MB budget of previous rounds)

    cast_w_kernel      <<<304, 256, 0, stream>>>(w1, w2, wd, wc1, wc2);
    clear_border_kernel<<<161, 256, 0, stream>>>(y1d);   // y1 border stays zero forever

    for (int b = 0; b < 2; ++b) {
        hipMemsetAsync(D,    0,    (size_t)NPIX * 128, stream);          // dense zeros
        hipMemsetAsync(grid, 0xFF, (size_t)HW * sizeof(int), stream);    // occupancy = -1

        scatter_dense_kernel<<<12800, 256, 0, stream>>>(features, coords, b, D, grid);

        conv_dense_kernel<false><<<3200, 256, 0, stream>>>(D,   nullptr, grid, wc1, b1, y1d, nullptr);
        conv_dense_kernel<true ><<<3200, 256, 0, stream>>>(y1d, D,       grid, wc2, b2, nullptr, out);
    }
}